// Round 1
// 144.312 us; speedup vs baseline: 1.0167x; 1.0167x over previous
//
#include <hip/hip_runtime.h>
#include <hip/hip_bf16.h>

#define BATCH 8
#define MAXPOS 2048
#define SEQ 2046
#define NH 12
#define HD 64
#define NCSLOT 254      // ci = c/16 in [-127,126], cslot = ci+127
#define TSTEPS 64       // K-chunks of 32 covering t=0..2047 (zero-padded past 2045)
#define PLANE (NH * HD) // 768

typedef __attribute__((ext_vector_type(4))) float floatx4;
typedef __attribute__((ext_vector_type(8))) short shortx8;

// ws layout: [Atile: 12*254*512 bf16 = 3,121,152 B][Vbf: 8*12*256*512 bf16 = 25,165,824 B]
#define ATILE_BYTES (NH * NCSLOT * 512 * 2)

#define GLOAD_LDS16(src, dst)                                                  \
    __builtin_amdgcn_global_load_lds(                                          \
        (const __attribute__((address_space(1))) void*)(src),                  \
        (__attribute__((address_space(3))) void*)(dst), 16, 0, 0)

// Block ranges inside prep_all
#define NB_V   (TSTEPS * NH * BATCH)   // 6144
#define NB_ZPB NH                      // 12
#define NB_A   (NCSLOT * NH)           // 3048

// ---------------------------------------------------------------------------
// prep_all: single prologue kernel (UNCHANGED this round).
//   [0,6144)        prep_V  : V -> bf16 B-fragments (LDS transpose, swizzled)
//   [6144,6156)     zpb     : O(S) prefix-scan  z_pb[1+n,h]=S(n)+S(SEQ-1-n)-E0
//   [6156,9204)     prep_A  : Toeplitz A-fragments, direct exp (2/thread)
//   [9204,9252)     zeros   : boundary rows of both outputs
// ---------------------------------------------------------------------------
__global__ __launch_bounds__(256)
void prep_all(const float* __restrict__ v, const float* __restrict__ w,
              const float* __restrict__ off, ushort* __restrict__ atile,
              ushort* __restrict__ vbf, float* __restrict__ out) {
    const int bi  = blockIdx.x;
    const int tid = threadIdx.x;

    if (bi < NB_V) {
        // ---- prep_V: block = (tc,h,b); col-swizzle (key=q*16) kills 4-way conflict
        __shared__ float Ls[32][64];
        const int tc = bi & 63;
        int rem = bi >> 6;
        const int h = rem % NH;
        const int b = rem / NH;
#pragma unroll
        for (int i = 0; i < 2; ++i) {
            int idx = tid + 256 * i;
            int row = idx >> 4;
            int c4  = (idx & 15) * 4;
            int key = (row >> 3) * 16;
            int t   = tc * 32 + row;
            float4 val = make_float4(0.f, 0.f, 0.f, 0.f);
            if (t < SEQ) val = *(const float4*)(v + ((size_t)(b * MAXPOS + 1 + t) * NH + h) * HD + c4);
            *(float4*)&Ls[row][c4 ^ key] = val;
        }
        __syncthreads();
        const int wv   = tid >> 6;
        const int lane = tid & 63;
        const int q    = lane >> 4;
        const int dcol = lane & 15;
        ushort pk[8];
#pragma unroll
        for (int j = 0; j < 8; ++j) {
            __hip_bfloat16 bv = __float2bfloat16(Ls[q * 8 + j][(wv * 16 + dcol) ^ (q * 16)]);
            pk[j] = *(ushort*)&bv;
        }
        *(uint4*)(vbf + ((size_t)((b * NH + h) * TSTEPS + tc) * 4 + wv) * 512 + lane * 8) = *(uint4*)pk;
    } else if (bi < NB_V + NB_ZPB) {
        // ---- zpb scan
        __shared__ float Es[SEQ];
        __shared__ float Ss[SEQ];
        __shared__ float wsum[4];
        const int h    = bi - NB_V;
        const int wid  = tid >> 6;
        const int lane = tid & 63;
        const float offh = off[h];
        const float* wh  = w + h * SEQ;
        for (int i = tid; i < SEQ; i += 256) Es[i] = __expf(wh[i] - offh);
        __syncthreads();
        const int base = tid * 8;
        float loc[8];
        float s = 0.f;
#pragma unroll
        for (int j = 0; j < 8; ++j) {
            float e = (base + j < SEQ) ? Es[base + j] : 0.f;
            s += e; loc[j] = s;
        }
        float sc = s;
#pragma unroll
        for (int d = 1; d < 64; d <<= 1) {
            float t = __shfl_up(sc, d);
            if (lane >= d) sc += t;
        }
        if (lane == 63) wsum[wid] = sc;
        __syncthreads();
        float woff = 0.f;
        for (int k = 0; k < wid; ++k) woff += wsum[k];
        float prefix = woff + sc - s;
#pragma unroll
        for (int j = 0; j < 8; ++j)
            if (base + j < SEQ) Ss[base + j] = prefix + loc[j];
        __syncthreads();
        const float E0 = Es[0];
        const size_t zb = (size_t)BATCH * MAXPOS * PLANE;
        for (int i = tid; i < SEQ; i += 256)
            out[zb + (size_t)(i + 1) * NH + h] = Ss[i] + Ss[SEQ - 1 - i] - E0;
    } else if (bi < NB_V + NB_ZPB + NB_A) {
        // ---- prep_A: tile (h,cslot) elem[lane][j]=exp(w[h,|16ci+(lane>>4)*8-(lane&15)+j|]-off)
        const int idx   = bi - NB_V - NB_ZPB;
        const int cslot = idx % NCSLOT;
        const int h     = idx / NCSLOT;
        const float offh = off[h];
        const float* wh  = w + h * SEQ;
        const int ci   = cslot - 127;
        const int lane = tid >> 2;
        const int jp   = (tid & 3) * 2;
        const int q    = lane >> 4;
        const int m    = lane & 15;
        const int d0   = 16 * ci + q * 8 - m + jp;
        ushort pk[2];
#pragma unroll
        for (int e = 0; e < 2; ++e) {
            int k = d0 + e; k = (k < 0) ? -k : k;
            float val = (k < SEQ) ? __expf(wh[k] - offh) : 0.f;
            __hip_bfloat16 bv = __float2bfloat16(val);
            pk[e] = *(ushort*)&bv;
        }
        *(ushort2*)(atile + ((size_t)(h * NCSLOT + cslot) * 512 + lane * 8 + jp)) = *(ushort2*)pk;
    } else {
        // ---- zero boundary positions (p=0, p=2047) of both outputs
        const int i = (bi - NB_V - NB_ZPB - NB_A) * 256 + tid;
        if (i < 2 * BATCH * PLANE) {
            int side = i / (BATCH * PLANE);
            int r    = i % (BATCH * PLANE);
            int b    = r / PLANE;
            int j    = r % PLANE;
            int p    = side ? (MAXPOS - 1) : 0;
            out[((size_t)b * MAXPOS + p) * PLANE + j] = 0.f;
        }
        if (i < 2 * NH) {
            size_t zb = (size_t)BATCH * MAXPOS * PLANE;
            int p = (i < NH) ? 0 : (MAXPOS - 1);
            out[zb + (size_t)p * NH + (i % NH)] = 0.f;
        }
    }
}

// ---------------------------------------------------------------------------
// gemm_pbv: R3 geometry (wave=64n x 64d x 1b, 4-wave blocks, 768 blocks =
// 3 blocks/CU uniform), NOW with a counted-vmcnt pipeline (T4) instead of
// __syncthreads():
//   - As[4] ring (32 KB): stage(tc+2) never WAR-conflicts with read(tc);
//     >=2 raw barriers always separate last read from overwrite issue.
//   - One fused "s_waitcnt vmcnt(6); s_barrier" per K-step: the 6 VMEM ops
//     of step tc+2 (2 global_load_lds + 4 B reg-loads) stay in flight across
//     the barrier; step tc+1's operands are guaranteed complete. vmcnt never
//     drains to 0 in the main loop (only in the peeled tail).
//   - "memory" clobbers pin region boundaries so the per-region VMEM count
//     is exactly 6 regardless of intra-region scheduling; an empty-asm fence
//     splits the prologue into two 6-op regions for the same reason.
//   - s_setprio(1/0) around the 16-MFMA cluster (T5).
// All indices in the unrolled body are compile-time (no runtime-indexed
// vector arrays -> no scratch).
// ---------------------------------------------------------------------------

#define FENCE    asm volatile("" ::: "memory")
#define WAITBAR6 asm volatile("s_waitcnt vmcnt(6)\n\ts_barrier" ::: "memory")
#define WAITBAR0 asm volatile("s_waitcnt vmcnt(0)\n\ts_barrier" ::: "memory")

// One K-step tc (K%4 == CK): read A(tc) from ring slot CK, stage A(tc+2) into
// slot NXT=(CK+2)&3, run 16 MFMA on b[BS] (BS = tc&1), then prefetch B(tc+2)
// into the just-freed b[BS]. STG=0 for the peeled tail steps (no prefetch).
#define GEMM_STEP(CK, NXT, BS, STG)                                            \
  do {                                                                         \
    shortx8 aa[4];                                                             \
    _Pragma("unroll")                                                          \
    for (int s = 0; s < 4; ++s)                                                \
        aa[s] = *(const shortx8*)(aRb + (CK) * 4096 + s * 512);                \
    if (STG) {                                                                 \
        GLOAD_LDS16(aQ + (CK) * 1024,       aWb + (NXT) * 4096);               \
        GLOAD_LDS16(aQ + (CK) * 1024 - 512, aWb + (NXT) * 4096 + 512);         \
    }                                                                          \
    __builtin_amdgcn_s_setprio(1);                                             \
    _Pragma("unroll")                                                          \
    for (int s = 0; s < 4; ++s)                                                \
        _Pragma("unroll")                                                      \
        for (int dt = 0; dt < 4; ++dt)                                         \
            acc[s][dt] = __builtin_amdgcn_mfma_f32_16x16x32_bf16(              \
                aa[s], b[BS][dt], acc[s][dt], 0, 0, 0);                        \
    __builtin_amdgcn_s_setprio(0);                                             \
    if (STG) {                                                                 \
        _Pragma("unroll")                                                      \
        for (int dt = 0; dt < 4; ++dt)                                         \
            b[BS][dt] = *(const shortx8*)(bQ + (CK) * 2048 + dt * 512);        \
    }                                                                          \
  } while (0)

__global__ __launch_bounds__(256, 3)
void gemm_pbv(const ushort* __restrict__ atile, const ushort* __restrict__ vbf,
              float* __restrict__ out) {
    __shared__ short As[4][8 * 512];   // 32 KB ring, 4 deep

    const int bid  = blockIdx.x;          // 0..767
    const int slot = bid >> 3;            // 0..95
    const int g    = (bid & 7) * 6 + (slot % 6);  // (h,bq) group 0..47
    const int nt   = slot / 6;            // 0..15
    const int h    = g >> 2;
    const int bq   = g & 3;
    const int tid  = threadIdx.x;
    const int wv   = tid >> 6;            // wave: sh = wv>>1, bw = wv&1
    const int lane = tid & 63;
    const int sh   = wv >> 1;
    const int bw   = wv & 1;
    const int bb   = bq * 2 + bw;

    floatx4 acc[4][4];
#pragma unroll
    for (int s = 0; s < 4; ++s)
#pragma unroll
        for (int dt = 0; dt < 4; ++dt) acc[s][dt] = (floatx4){0.f, 0.f, 0.f, 0.f};

    // A staging: wave wv stages frags fs = 2wv, 2wv+1.
    // cslot(tc, fs) = 2*tc - (nt*8 + fs) + 127   (always in [0,253])
    const ushort* aS = atile + ((size_t)h * NCSLOT + (127 - nt * 8 - 2 * wv)) * 512 + lane * 8;
    const ushort* bP = vbf + (size_t)(bb * NH + h) * (TSTEPS * 4 * 512) + lane * 8;
    short* aWb = &As[0][2 * wv * 512];                        // stage dest, + ring*4096
    const short* aRb = &As[0][sh * 4 * 512] + lane * 8;       // frag read,  + ring*4096

    shortx8 b[2][4];

    // ---- prologue: S(0) region [6 VMEM], fence, S(1) region [6 VMEM]
    GLOAD_LDS16(aS,       aWb);
    GLOAD_LDS16(aS - 512, aWb + 512);
#pragma unroll
    for (int dt = 0; dt < 4; ++dt) b[0][dt] = *(const shortx8*)(bP + dt * 512);
    FENCE;  // region split: newest-6 at the wait below is exactly S(1)
    GLOAD_LDS16(aS + 1024, aWb + 4096);
    GLOAD_LDS16(aS + 512,  aWb + 4096 + 512);
#pragma unroll
    for (int dt = 0; dt < 4; ++dt) b[1][dt] = *(const shortx8*)(bP + 2048 + dt * 512);
    WAITBAR6;   // S(0) complete (A(0) in LDS for all waves, B(0) in regs)

    // stage/prefetch source cursors for step tc+2 (tc = 4u + CK)
    const ushort* aQ = aS + 2 * 1024;
    const ushort* bQ = bP + 2 * 2048;

    // ---- main loop: tc = 0..59, every step stages S(tc+2), waits vmcnt(6)
    for (int u = 0; u < 15; ++u) {
        GEMM_STEP(0, 2, 0, 1); WAITBAR6;
        GEMM_STEP(1, 3, 1, 1); WAITBAR6;
        GEMM_STEP(2, 0, 0, 1); WAITBAR6;
        GEMM_STEP(3, 1, 1, 1); WAITBAR6;
        aQ += 4 * 1024;
        bQ += 4 * 2048;
    }
    // ---- peeled tail: tc = 60..63 (aQ now points at S(62) source)
    GEMM_STEP(0, 2, 0, 1); WAITBAR6;   // tc=60: stages S(62); newest-6 = S(62)
    GEMM_STEP(1, 3, 1, 1); WAITBAR6;   // tc=61: stages S(63); newest-6 = S(63)
    GEMM_STEP(2, 0, 0, 0); WAITBAR0;   // tc=62: no stage; drain S(63)
    GEMM_STEP(3, 1, 1, 0);             // tc=63: final compute, no wait

    // epilogue: D row=(lane>>4)*4+r (n-local), col=lane&15 (d-local)
    const int q    = lane >> 4;
    const int dcol = lane & 15;
    const int nB   = nt * 128 + sh * 64;
#pragma unroll
    for (int s = 0; s < 4; ++s) {
        int nsb = nB + s * 16 + q * 4;
#pragma unroll
        for (int r = 0; r < 4; ++r) {
            int n = nsb + r;
            if (n < SEQ) {
                float* ob = out + ((size_t)(bb * MAXPOS + 1 + n) * NH + h) * HD + dcol;
#pragma unroll
                for (int dt = 0; dt < 4; ++dt) ob[dt * 16] = acc[s][dt][r];
            }
        }
    }
}

extern "C" void kernel_launch(void* const* d_in, const int* in_sizes, int n_in,
                              void* d_out, int out_size, void* d_ws, size_t ws_size,
                              hipStream_t stream) {
    const float* v   = (const float*)d_in[0];  // (8, 2048, 12, 64)
    const float* off = (const float*)d_in[1];  // (1, 12)
    const float* w   = (const float*)d_in[2];  // (1, 12, 2046)
    float* out = (float*)d_out;

    ushort* atile = (ushort*)d_ws;
    ushort* vbf   = (ushort*)((char*)d_ws + ATILE_BYTES);

    prep_all<<<NB_V + NB_ZPB + NB_A + 48, 256, 0, stream>>>(v, w, off, atile, vbf, out);
    gemm_pbv<<<768, 256, 0, stream>>>(atile, vbf, out);
}